// Round 8
// baseline (591.110 us; speedup 1.0000x reference)
//
#include <hip/hip_runtime.h>
#include <hip/hip_bf16.h>

#define N_NODES 100000
#define N_EDGES 1000000
#define DIM 64
#define NORM_INV 0.01f
#define LN_EPS 1e-5f
#define N_TILES 6250          // N_NODES/16
#define PROJ_BLOCKS 1563      // ceil(6250/4)
#define N_BUCKETS 782         // ceil(100000/128), 128 rows per bucket
#define HISTB 489             // ceil(1e6/2048)
#define L2E 1.4426950408889634f
#define LN2 0.6931471805599453f

typedef __attribute__((ext_vector_type(8))) short short8;
typedef __attribute__((ext_vector_type(4))) float f32x4;

__device__ __forceinline__ unsigned short f2bf(float f) {
    union { float f; unsigned u; } x; x.f = f;
    unsigned r = x.u + 0x7FFFu + ((x.u >> 16) & 1u);
    return (unsigned short)(r >> 16);
}
__device__ __forceinline__ float bf2f(unsigned short s) {
    union { unsigned u; float f; } x; x.u = ((unsigned)s) << 16; return x.f;
}

// DPP tree-add over 16 contiguous lanes. ctrl must be a compile-time constant
// -> template parameter.
template <int CTRL>
__device__ __forceinline__ float dpp_add(float v) {
    int t = __builtin_amdgcn_update_dpp(0, __float_as_int(v), CTRL, 0xF, 0xF, true);
    return v + __int_as_float(t);
}
__device__ __forceinline__ float red16(float v) {
    v = dpp_add<0xB1>(v);    // quad_perm [1,0,3,2]  (xor 1)
    v = dpp_add<0x4E>(v);    // quad_perm [2,3,0,1]  (xor 2)
    v = dpp_add<0x124>(v);   // row_ror:4
    v = dpp_add<0x128>(v);   // row_ror:8
    return v;
}
__device__ __forceinline__ float red64(float v) {
    v = red16(v);
    v += __shfl_xor(v, 16);
    v += __shfl_xor(v, 32);
    return v;
}

// ---------------------------------------------------------------------------
// P0 (2 blocks): block 0 = MFMA weight fragments (W1a/W1b pre-scaled by
// log2e); block 1 = zero bucketCnt + epilogue table tab2[f]={w2*ln2, w1c*l2e}.
// ---------------------------------------------------------------------------
__global__ __launch_bounds__(256) void prep_frags(
    const float* __restrict__ W, const float* __restrict__ att_W1,
    const float* __restrict__ att_W2,
    short8* __restrict__ whi, short8* __restrict__ wlo,
    short8* __restrict__ wa, short8* __restrict__ wb,
    float2* __restrict__ tab2, int* __restrict__ bucketCnt) {
    if (blockIdx.x == 1) {
        for (int i = threadIdx.x; i < N_BUCKETS; i += 256) bucketCnt[i] = 0;
        if (threadIdx.x < 64) {
            const int f = threadIdx.x;
            tab2[f] = make_float2(att_W2[f] * LN2, att_W1[f * 129 + 128] * L2E);
        }
        return;
    }
    const int l = threadIdx.x & 63;
    const int nt = threadIdx.x >> 6;
    const int c = l & 15, q = l >> 4;
    const int n = nt * 16 + c;
#pragma unroll
    for (int ks = 0; ks < 2; ++ks) {
        const int k0 = ks * 32 + q * 8;
        short8 hi8, lo8, a8, b8;
#pragma unroll
        for (int jj = 0; jj < 8; ++jj) {
            float w = W[n * 64 + k0 + jj];
            unsigned short hh = f2bf(w);
            hi8[jj] = (short)hh;
            lo8[jj] = (short)f2bf(w - bf2f(hh));
            a8[jj] = (short)f2bf(att_W1[n * 129 + k0 + jj] * L2E);
            b8[jj] = (short)f2bf(att_W1[n * 129 + 64 + k0 + jj] * L2E);
        }
        const int idx = (nt * 2 + ks) * 64 + l;
        whi[idx] = hi8; wlo[idx] = lo8; wa[idx] = a8; wb[idx] = b8;
    }
}

// ---------------------------------------------------------------------------
// P1 fat kernel. blocks [0,PROJ_BLOCKS): MFMA projection, 1 tile/wave.
//   x = h@W^T + b (hi/lo bf16 split), u = (x@W1a^T + b1)*log2e,
//   v = x@W1b^T*log2e.  xv[node] 256B interleaved {x4|v4}; u_bf permuted bf16.
// blocks [PROJ_BLOCKS, +HISTB): bucket histogram (LDS-staged).
// ---------------------------------------------------------------------------
__global__ __launch_bounds__(256) void proj_hist(
    const float* __restrict__ h, const float* __restrict__ bl,
    const float* __restrict__ att_b1,
    const short8* __restrict__ whi, const short8* __restrict__ wlo,
    const short8* __restrict__ wa, const short8* __restrict__ wb,
    const int* __restrict__ edges, int* __restrict__ bucketCnt,
    unsigned short* __restrict__ xv, unsigned short* __restrict__ u_bf) {
    if (blockIdx.x >= PROJ_BLOCKS) {
        __shared__ int lh[N_BUCKETS];
        const int tid = threadIdx.x;
        for (int i = tid; i < N_BUCKETS; i += 256) lh[i] = 0;
        __syncthreads();
        const int e0 = (blockIdx.x - PROJ_BLOCKS) * 2048;
#pragma unroll
        for (int i = 0; i < 8; ++i) {
            const int e = e0 + tid * 8 + i;
            if (e < N_EDGES) atomicAdd(&lh[edges[e] >> 7], 1);
        }
        __syncthreads();
        for (int b = tid; b < N_BUCKETS; b += 256)
            if (lh[b]) atomicAdd(&bucketCnt[b], lh[b]);
        return;
    }
    __shared__ __align__(16) unsigned short lds[4][16 * 72];
    const int lane = threadIdx.x & 63;
    const int wv = threadIdx.x >> 6;
    const int c = lane & 15, q = lane >> 4;
    const int tile = blockIdx.x * 4 + wv;
    if (tile >= N_TILES) return;
    const int n0 = tile * 16;

    short8 Whi[4][2], Wlo[4][2], Wa[4][2], Wb[4][2];
    float bias[4], b1L[4];
#pragma unroll
    for (int nt = 0; nt < 4; ++nt) {
        bias[nt] = bl[nt * 16 + c];
        b1L[nt] = att_b1[nt * 16 + c] * L2E;
#pragma unroll
        for (int ks = 0; ks < 2; ++ks) {
            const int idx = (nt * 2 + ks) * 64 + lane;
            Whi[nt][ks] = whi[idx]; Wlo[nt][ks] = wlo[idx];
            Wa[nt][ks] = wa[idx];   Wb[nt][ks] = wb[idx];
        }
    }

    short8 Ahi[2], Alo[2];
#pragma unroll
    for (int ks = 0; ks < 2; ++ks) {
        const float* hp = h + (size_t)(n0 + c) * 64 + ks * 32 + q * 8;
        f32x4 p0 = *(const f32x4*)hp;
        f32x4 p1 = *(const f32x4*)(hp + 4);
        short8 hi8, lo8;
#pragma unroll
        for (int jj = 0; jj < 4; ++jj) {
            unsigned short hh = f2bf(p0[jj]);
            hi8[jj] = (short)hh; lo8[jj] = (short)f2bf(p0[jj] - bf2f(hh));
            unsigned short h2 = f2bf(p1[jj]);
            hi8[4 + jj] = (short)h2; lo8[4 + jj] = (short)f2bf(p1[jj] - bf2f(h2));
        }
        Ahi[ks] = hi8; Alo[ks] = lo8;
    }

    f32x4 xacc[4] = {{0,0,0,0},{0,0,0,0},{0,0,0,0},{0,0,0,0}};
#pragma unroll
    for (int ks = 0; ks < 2; ++ks)
#pragma unroll
        for (int nt = 0; nt < 4; ++nt) {
            xacc[nt] = __builtin_amdgcn_mfma_f32_16x16x32_bf16(Ahi[ks], Whi[nt][ks], xacc[nt], 0, 0, 0);
            xacc[nt] = __builtin_amdgcn_mfma_f32_16x16x32_bf16(Ahi[ks], Wlo[nt][ks], xacc[nt], 0, 0, 0);
            xacc[nt] = __builtin_amdgcn_mfma_f32_16x16x32_bf16(Alo[ks], Whi[nt][ks], xacc[nt], 0, 0, 0);
        }

    unsigned short* lw = lds[wv];
#pragma unroll
    for (int r = 0; r < 4; ++r) {
        const int node = n0 + q * 4 + r;
        unsigned short xb[4];
#pragma unroll
        for (int nt = 0; nt < 4; ++nt) {
            unsigned short v16 = f2bf(xacc[nt][r] + bias[nt]);
            xb[nt] = v16;
            lw[(q * 4 + r) * 72 + nt * 16 + c] = v16;
        }
        uint2 pk;
        pk.x = (unsigned)xb[0] | ((unsigned)xb[1] << 16);
        pk.y = (unsigned)xb[2] | ((unsigned)xb[3] << 16);
        *(uint2*)(xv + (size_t)node * 128 + c * 8) = pk;
    }

    short8 Ax[2];
#pragma unroll
    for (int ks = 0; ks < 2; ++ks)
        Ax[ks] = *(const short8*)&lw[c * 72 + ks * 32 + q * 8];

    f32x4 uacc[4] = {{0,0,0,0},{0,0,0,0},{0,0,0,0},{0,0,0,0}};
    f32x4 vacc[4] = {{0,0,0,0},{0,0,0,0},{0,0,0,0},{0,0,0,0}};
#pragma unroll
    for (int ks = 0; ks < 2; ++ks)
#pragma unroll
        for (int nt = 0; nt < 4; ++nt) {
            uacc[nt] = __builtin_amdgcn_mfma_f32_16x16x32_bf16(Ax[ks], Wa[nt][ks], uacc[nt], 0, 0, 0);
            vacc[nt] = __builtin_amdgcn_mfma_f32_16x16x32_bf16(Ax[ks], Wb[nt][ks], vacc[nt], 0, 0, 0);
        }
#pragma unroll
    for (int r = 0; r < 4; ++r) {
        const int node = n0 + q * 4 + r;
        uint2 pu;
        pu.x = (unsigned)f2bf(uacc[0][r] + b1L[0]) | ((unsigned)f2bf(uacc[1][r] + b1L[1]) << 16);
        pu.y = (unsigned)f2bf(uacc[2][r] + b1L[2]) | ((unsigned)f2bf(uacc[3][r] + b1L[3]) << 16);
        *(uint2*)(u_bf + (size_t)node * 64 + c * 4) = pu;
        uint2 pk;
        pk.x = (unsigned)f2bf(vacc[0][r]) | ((unsigned)f2bf(vacc[1][r]) << 16);
        pk.y = (unsigned)f2bf(vacc[2][r]) | ((unsigned)f2bf(vacc[3][r]) << 16);
        *(uint2*)(xv + (size_t)node * 128 + c * 8 + 4) = pk;
    }
}

// ---------------------------------------------------------------------------
// scanA: exclusive scan of bucketCnt -> baseA + cursA.
// ---------------------------------------------------------------------------
__global__ __launch_bounds__(1024) void scanA(
    const int* __restrict__ bucketCnt, int* __restrict__ baseA,
    int* __restrict__ cursA) {
    __shared__ int wsum[16];
    const int t = threadIdx.x, lane = t & 63, w = t >> 6;
    const int v = (t < N_BUCKETS) ? bucketCnt[t] : 0;
    int sc = v;
#pragma unroll
    for (int off = 1; off < 64; off <<= 1) {
        int u = __shfl_up(sc, off);
        if (lane >= off) sc += u;
    }
    if (lane == 63) wsum[w] = sc;
    __syncthreads();
    if (w == 0) {
        int x = (lane < 16) ? wsum[lane] : 0;
#pragma unroll
        for (int off = 1; off < 16; off <<= 1) {
            int u = __shfl_up(x, off);
            if (lane >= off) x += u;
        }
        if (lane < 16) wsum[lane] = x;
    }
    __syncthreads();
    const int excl = sc - v + ((w > 0) ? wsum[w - 1] : 0);
    if (t < N_BUCKETS) { baseA[t] = excl; cursA[t] = excl; }
    if (t == N_BUCKETS - 1) baseA[N_BUCKETS] = excl + v;
}

// ---------------------------------------------------------------------------
// scatterA: stage edges into bucket regions (block-burst claims).
// rec = {col | lrow<<17, dist(bf16 lo) | emask*0.01 (bf16 hi)}
// ---------------------------------------------------------------------------
__global__ __launch_bounds__(256) void scatterA(
    const int* __restrict__ edges, const float* __restrict__ dist,
    const float* __restrict__ emask, int* __restrict__ cursA,
    uint2* __restrict__ srec) {
    __shared__ int lh[N_BUCKETS];
    __shared__ int lb[N_BUCKETS];
    const int tid = threadIdx.x;
    for (int i = tid; i < N_BUCKETS; i += 256) lh[i] = 0;
    __syncthreads();

    const int e0 = blockIdx.x * 2048 + tid * 8;
    int row[8], col[8];
    unsigned de[8];
#pragma unroll
    for (int i = 0; i < 8; ++i) {
        const int e = e0 + i;
        if (e < N_EDGES) {
            row[i] = edges[e];
            col[i] = edges[N_EDGES + e];
            de[i] = (unsigned)f2bf(dist[e]) | ((unsigned)f2bf(emask[e] * NORM_INV) << 16);
            atomicAdd(&lh[row[i] >> 7], 1);
        } else {
            row[i] = -1;
        }
    }
    __syncthreads();
    for (int b = tid; b < N_BUCKETS; b += 256) {
        const int c = lh[b];
        lb[b] = c ? atomicAdd(&cursA[b], c) : 0;
    }
    __syncthreads();
    for (int i = tid; i < N_BUCKETS; i += 256) lh[i] = 0;
    __syncthreads();
#pragma unroll
    for (int i = 0; i < 8; ++i) {
        if (row[i] >= 0) {
            const int bk = row[i] >> 7;
            const int rk = atomicAdd(&lh[bk], 1);
            uint2 rc;
            rc.x = (unsigned)col[i] | ((unsigned)(row[i] & 127) << 17);
            rc.y = de[i];
            srec[lb[bk] + rk] = rc;
        }
    }
}

// ---------------------------------------------------------------------------
// agg_bucket: one block per 128-row bucket. u staged in LDS (16 KB); fp32
// accumulators for 128 rows x 64 feats in LDS (32 KB, ds_add). Waves
// process 4 edges/iter (slot = lane>>4, j = lane&15); 16-lane attention
// reduction via DPP (VALU pipe). Fused residual + LN + SiLU epilogue.
// ---------------------------------------------------------------------------
__global__ __launch_bounds__(256, 3) void agg_bucket(
    const int* __restrict__ baseA, const uint2* __restrict__ srec,
    const unsigned short* __restrict__ xv, const unsigned short* __restrict__ u_bf,
    const float2* __restrict__ tab2, const float* __restrict__ att_b2,
    const float* __restrict__ ln_g, const float* __restrict__ ln_b,
    float* __restrict__ out) {
    __shared__ __align__(16) float acc[128 * 64];          // 32 KB
    __shared__ __align__(16) unsigned short uld[128 * 64]; // 16 KB

    const int tid = threadIdx.x;
    const int lane = tid & 63;
    const int wv = tid >> 6;
    const int j = lane & 15;
    const int s = lane >> 4;
    const int b = blockIdx.x;
    const int row0 = b * 128;
    const int nrows = min(128, N_NODES - row0);

    // stage u (coalesced) + zero acc
    {
        uint4* u4 = (uint4*)uld;
        const uint4* ug = (const uint4*)(u_bf + (size_t)row0 * 64);
        for (int i = tid; i < 1024; i += 256) u4[i] = ug[i];
        f32x4* a4 = (f32x4*)acc;
        const f32x4 z = {0.f, 0.f, 0.f, 0.f};
        for (int i = tid; i < 2048; i += 256) a4[i] = z;
    }
    __syncthreads();

    // per-lane constants
    const float2 t0 = tab2[j], t1 = tab2[j + 16], t2 = tab2[j + 32], t3 = tab2[j + 48];
    const float b2L = att_b2[0] * L2E;
    const int s0 = baseA[b];
    const int s1 = baseA[b + 1];
    const unsigned* xvu = (const unsigned*)xv;

    int e = s0 + wv * 4;
    if (e < s1) {
        int ia = min(e + s, s1 - 1);
        uint2 recA = srec[ia];
        uint4 xvA = *(const uint4*)(xvu + (size_t)(recA.x & 0x1FFFF) * 64 + j * 4);
        int ib = min(e + 16 + s, s1 - 1);
        uint2 recB = srec[ib];
        for (; e < s1; e += 16) {
            const int ic = min(e + 32 + s, s1 - 1);
            const uint2 recC = srec[ic];
            const uint4 xvB = *(const uint4*)(xvu + (size_t)(recB.x & 0x1FFFF) * 64 + j * 4);

            const float dist = __uint_as_float(recA.y << 16);
            const float emN = ((e + s) < s1) ? __uint_as_float(recA.y & 0xffff0000u) : 0.f;
            const int lrow = (int)(recA.x >> 17);
            const uint2 uu = *(const uint2*)&uld[lrow * 64 + j * 4];
            const float u0 = __uint_as_float(uu.x << 16);
            const float u1 = __uint_as_float(uu.x & 0xffff0000u);
            const float u2 = __uint_as_float(uu.y << 16);
            const float u3 = __uint_as_float(uu.y & 0xffff0000u);
            const float x0 = __uint_as_float(xvA.x << 16);
            const float x1 = __uint_as_float(xvA.x & 0xffff0000u);
            const float x2 = __uint_as_float(xvA.y << 16);
            const float x3 = __uint_as_float(xvA.y & 0xffff0000u);
            const float v0 = __uint_as_float(xvA.z << 16);
            const float v1 = __uint_as_float(xvA.z & 0xffff0000u);
            const float v2 = __uint_as_float(xvA.w << 16);
            const float v3 = __uint_as_float(xvA.w & 0xffff0000u);

            float pv = 0.f, pre, sg;
            pre = fmaf(dist, t0.y, u0) + v0;
            sg = __builtin_amdgcn_rcpf(1.f + __builtin_amdgcn_exp2f(-pre));
            pv = fmaf(pre * sg, t0.x, pv);
            pre = fmaf(dist, t1.y, u1) + v1;
            sg = __builtin_amdgcn_rcpf(1.f + __builtin_amdgcn_exp2f(-pre));
            pv = fmaf(pre * sg, t1.x, pv);
            pre = fmaf(dist, t2.y, u2) + v2;
            sg = __builtin_amdgcn_rcpf(1.f + __builtin_amdgcn_exp2f(-pre));
            pv = fmaf(pre * sg, t2.x, pv);
            pre = fmaf(dist, t3.y, u3) + v3;
            sg = __builtin_amdgcn_rcpf(1.f + __builtin_amdgcn_exp2f(-pre));
            pv = fmaf(pre * sg, t3.x, pv);

            pv = red16(pv);  // DPP: VALU pipe, no LDS
            const float sp = fmaf(pv, L2E, b2L);
            const float att =
                emN * __builtin_amdgcn_rcpf(1.f + __builtin_amdgcn_exp2f(-sp));

            float* ar = acc + lrow * 64 + j * 4;
            atomicAdd(ar + 0, att * x0);
            atomicAdd(ar + 1, att * x1);
            atomicAdd(ar + 2, att * x2);
            atomicAdd(ar + 3, att * x3);

            recA = recB; xvA = xvB; recB = recC;
        }
    }
    __syncthreads();

    // LN + SiLU epilogue: wave per row, lane = feature
    const int f = lane;
    const int jj = f & 15, kk = f >> 4;
    const float gv = ln_g[f], bv = ln_b[f];
    for (int r = wv; r < nrows; r += 4) {
        const int node = row0 + r;
        const float a = acc[r * 64 + jj * 4 + kk];
        const float xres = bf2f(xv[(size_t)node * 128 + jj * 8 + kk]);
        const float o = xres + a;
        const float sm = red64(o);
        const float sq = red64(o * o);
        const float mu = sm * (1.f / 64.f);
        const float var = sq * (1.f / 64.f) - mu * mu;
        const float rstd = rsqrtf(var + LN_EPS);
        const float y = fmaf((o - mu) * rstd, gv, bv);
        out[(size_t)node * 64 + f] =
            y * __builtin_amdgcn_rcpf(1.f + __builtin_amdgcn_exp2f(-y * L2E));
    }
}

extern "C" void kernel_launch(void* const* d_in, const int* in_sizes, int n_in,
                              void* d_out, int out_size, void* d_ws, size_t ws_size,
                              hipStream_t stream) {
    const float* h      = (const float*)d_in[0];
    const float* dist   = (const float*)d_in[1];
    const int*   edges  = (const int*)d_in[2];
    const float* emask  = (const float*)d_in[4];
    const float* W_lin  = (const float*)d_in[5];
    const float* b_lin  = (const float*)d_in[6];
    const float* att_W1 = (const float*)d_in[7];
    const float* att_b1 = (const float*)d_in[8];
    const float* att_W2 = (const float*)d_in[9];
    const float* att_b2 = (const float*)d_in[10];
    const float* ln_g   = (const float*)d_in[11];
    const float* ln_b   = (const float*)d_in[12];
    float* out = (float*)d_out;

    char* ws = (char*)d_ws;
    unsigned short* xv   = (unsigned short*)ws;                  // 25.6 MB
    unsigned short* u_bf = (unsigned short*)(ws + 25600000);     // 12.8 MB
    uint2* srec          = (uint2*)(ws + 38400000);              // 8 MB
    int* bucketCnt       = (int*)(ws + 46400000);
    int* baseA           = (int*)(ws + 46403200);
    int* cursA           = (int*)(ws + 46406400);
    float2* tab2         = (float2*)(ws + 46409600);
    short8* whi          = (short8*)(ws + 46410112);
    short8* wlo          = (short8*)(ws + 46418304);
    short8* wa           = (short8*)(ws + 46426496);
    short8* wb           = (short8*)(ws + 46434688);

    prep_frags<<<2, 256, 0, stream>>>(W_lin, att_W1, att_W2, whi, wlo, wa, wb,
                                      tab2, bucketCnt);
    proj_hist<<<PROJ_BLOCKS + HISTB, 256, 0, stream>>>(
        h, b_lin, att_b1, whi, wlo, wa, wb, edges, bucketCnt, xv, u_bf);
    scanA<<<1, 1024, 0, stream>>>(bucketCnt, baseA, cursA);
    scatterA<<<HISTB, 256, 0, stream>>>(edges, dist, emask, cursA, srec);
    agg_bucket<<<N_BUCKETS, 256, 0, stream>>>(baseA, srec, xv, u_bf, tab2,
                                              att_b2, ln_g, ln_b, out);
}

// Round 10
// 241.618 us; speedup vs baseline: 2.4465x; 2.4465x over previous
//
#include <hip/hip_runtime.h>
#include <hip/hip_bf16.h>

#define N_NODES 100000
#define N_EDGES 1000000
#define DIM 64
#define NORM_INV 0.01f
#define LN_EPS 1e-5f
#define N_TILES 6250          // N_NODES/16
#define PROJ_BLOCKS 1563      // ceil(6250/4)
#define N_BUCKETS 1563        // ceil(100000/64), 64 rows per bucket
#define HISTB 489             // ceil(1e6/2048)
#define L2E 1.4426950408889634f
#define LN2 0.6931471805599453f

typedef __attribute__((ext_vector_type(8))) short short8;
typedef __attribute__((ext_vector_type(4))) float f32x4;

__device__ __forceinline__ unsigned short f2bf(float f) {
    union { float f; unsigned u; } x; x.f = f;
    unsigned r = x.u + 0x7FFFu + ((x.u >> 16) & 1u);
    return (unsigned short)(r >> 16);
}
__device__ __forceinline__ float bf2f(unsigned short s) {
    union { unsigned u; float f; } x; x.u = ((unsigned)s) << 16; return x.f;
}

template <int CTRL>
__device__ __forceinline__ float dpp_add(float v) {
    int t = __builtin_amdgcn_update_dpp(0, __float_as_int(v), CTRL, 0xF, 0xF, true);
    return v + __int_as_float(t);
}
__device__ __forceinline__ float red16(float v) {
    v = dpp_add<0xB1>(v);    // quad_perm xor1
    v = dpp_add<0x4E>(v);    // quad_perm xor2
    v = dpp_add<0x124>(v);   // row_ror:4
    v = dpp_add<0x128>(v);   // row_ror:8
    return v;
}
__device__ __forceinline__ float red64(float v) {
    v = red16(v);
    v += __shfl_xor(v, 16);
    v += __shfl_xor(v, 32);
    return v;
}

// ---------------------------------------------------------------------------
// P0 (2 blocks): block 0 = MFMA weight fragments; block 1 = zero bucketCnt +
// epilogue table tab2[f]={w2*ln2, w1c*log2e}.
// ---------------------------------------------------------------------------
__global__ __launch_bounds__(256) void prep_frags(
    const float* __restrict__ W, const float* __restrict__ att_W1,
    const float* __restrict__ att_W2,
    short8* __restrict__ whi, short8* __restrict__ wlo,
    short8* __restrict__ wa, short8* __restrict__ wb,
    float2* __restrict__ tab2, int* __restrict__ bucketCnt) {
    if (blockIdx.x == 1) {
        for (int i = threadIdx.x; i < N_BUCKETS; i += 256) bucketCnt[i] = 0;
        if (threadIdx.x < 64) {
            const int f = threadIdx.x;
            tab2[f] = make_float2(att_W2[f] * LN2, att_W1[f * 129 + 128] * L2E);
        }
        return;
    }
    const int l = threadIdx.x & 63;
    const int nt = threadIdx.x >> 6;
    const int c = l & 15, q = l >> 4;
    const int n = nt * 16 + c;
#pragma unroll
    for (int ks = 0; ks < 2; ++ks) {
        const int k0 = ks * 32 + q * 8;
        short8 hi8, lo8, a8, b8;
#pragma unroll
        for (int jj = 0; jj < 8; ++jj) {
            float w = W[n * 64 + k0 + jj];
            unsigned short hh = f2bf(w);
            hi8[jj] = (short)hh;
            lo8[jj] = (short)f2bf(w - bf2f(hh));
            a8[jj] = (short)f2bf(att_W1[n * 129 + k0 + jj] * L2E);
            b8[jj] = (short)f2bf(att_W1[n * 129 + 64 + k0 + jj] * L2E);
        }
        const int idx = (nt * 2 + ks) * 64 + l;
        whi[idx] = hi8; wlo[idx] = lo8; wa[idx] = a8; wb[idx] = b8;
    }
}

// ---------------------------------------------------------------------------
// P1 fat kernel: MFMA projection (1 tile/wave) + bucket histogram blocks.
// ---------------------------------------------------------------------------
__global__ __launch_bounds__(256) void proj_hist(
    const float* __restrict__ h, const float* __restrict__ bl,
    const float* __restrict__ att_b1,
    const short8* __restrict__ whi, const short8* __restrict__ wlo,
    const short8* __restrict__ wa, const short8* __restrict__ wb,
    const int* __restrict__ edges, int* __restrict__ bucketCnt,
    unsigned short* __restrict__ xv, unsigned short* __restrict__ u_bf) {
    if (blockIdx.x >= PROJ_BLOCKS) {
        __shared__ int lh[N_BUCKETS];
        const int tid = threadIdx.x;
        for (int i = tid; i < N_BUCKETS; i += 256) lh[i] = 0;
        __syncthreads();
        const int e0 = (blockIdx.x - PROJ_BLOCKS) * 2048;
#pragma unroll
        for (int i = 0; i < 8; ++i) {
            const int e = e0 + tid * 8 + i;
            if (e < N_EDGES) atomicAdd(&lh[edges[e] >> 6], 1);
        }
        __syncthreads();
        for (int b = tid; b < N_BUCKETS; b += 256)
            if (lh[b]) atomicAdd(&bucketCnt[b], lh[b]);
        return;
    }
    __shared__ __align__(16) unsigned short lds[4][16 * 72];
    const int lane = threadIdx.x & 63;
    const int wv = threadIdx.x >> 6;
    const int c = lane & 15, q = lane >> 4;
    const int tile = blockIdx.x * 4 + wv;
    if (tile >= N_TILES) return;
    const int n0 = tile * 16;

    short8 Whi[4][2], Wlo[4][2], Wa[4][2], Wb[4][2];
    float bias[4], b1L[4];
#pragma unroll
    for (int nt = 0; nt < 4; ++nt) {
        bias[nt] = bl[nt * 16 + c];
        b1L[nt] = att_b1[nt * 16 + c] * L2E;
#pragma unroll
        for (int ks = 0; ks < 2; ++ks) {
            const int idx = (nt * 2 + ks) * 64 + lane;
            Whi[nt][ks] = whi[idx]; Wlo[nt][ks] = wlo[idx];
            Wa[nt][ks] = wa[idx];   Wb[nt][ks] = wb[idx];
        }
    }

    short8 Ahi[2], Alo[2];
#pragma unroll
    for (int ks = 0; ks < 2; ++ks) {
        const float* hp = h + (size_t)(n0 + c) * 64 + ks * 32 + q * 8;
        f32x4 p0 = *(const f32x4*)hp;
        f32x4 p1 = *(const f32x4*)(hp + 4);
        short8 hi8, lo8;
#pragma unroll
        for (int jj = 0; jj < 4; ++jj) {
            unsigned short hh = f2bf(p0[jj]);
            hi8[jj] = (short)hh; lo8[jj] = (short)f2bf(p0[jj] - bf2f(hh));
            unsigned short h2 = f2bf(p1[jj]);
            hi8[4 + jj] = (short)h2; lo8[4 + jj] = (short)f2bf(p1[jj] - bf2f(h2));
        }
        Ahi[ks] = hi8; Alo[ks] = lo8;
    }

    f32x4 xacc[4] = {{0,0,0,0},{0,0,0,0},{0,0,0,0},{0,0,0,0}};
#pragma unroll
    for (int ks = 0; ks < 2; ++ks)
#pragma unroll
        for (int nt = 0; nt < 4; ++nt) {
            xacc[nt] = __builtin_amdgcn_mfma_f32_16x16x32_bf16(Ahi[ks], Whi[nt][ks], xacc[nt], 0, 0, 0);
            xacc[nt] = __builtin_amdgcn_mfma_f32_16x16x32_bf16(Ahi[ks], Wlo[nt][ks], xacc[nt], 0, 0, 0);
            xacc[nt] = __builtin_amdgcn_mfma_f32_16x16x32_bf16(Alo[ks], Whi[nt][ks], xacc[nt], 0, 0, 0);
        }

    unsigned short* lw = lds[wv];
#pragma unroll
    for (int r = 0; r < 4; ++r) {
        const int node = n0 + q * 4 + r;
        unsigned short xb[4];
#pragma unroll
        for (int nt = 0; nt < 4; ++nt) {
            unsigned short v16 = f2bf(xacc[nt][r] + bias[nt]);
            xb[nt] = v16;
            lw[(q * 4 + r) * 72 + nt * 16 + c] = v16;
        }
        uint2 pk;
        pk.x = (unsigned)xb[0] | ((unsigned)xb[1] << 16);
        pk.y = (unsigned)xb[2] | ((unsigned)xb[3] << 16);
        *(uint2*)(xv + (size_t)node * 128 + c * 8) = pk;
    }

    short8 Ax[2];
#pragma unroll
    for (int ks = 0; ks < 2; ++ks)
        Ax[ks] = *(const short8*)&lw[c * 72 + ks * 32 + q * 8];

    f32x4 uacc[4] = {{0,0,0,0},{0,0,0,0},{0,0,0,0},{0,0,0,0}};
    f32x4 vacc[4] = {{0,0,0,0},{0,0,0,0},{0,0,0,0},{0,0,0,0}};
#pragma unroll
    for (int ks = 0; ks < 2; ++ks)
#pragma unroll
        for (int nt = 0; nt < 4; ++nt) {
            uacc[nt] = __builtin_amdgcn_mfma_f32_16x16x32_bf16(Ax[ks], Wa[nt][ks], uacc[nt], 0, 0, 0);
            vacc[nt] = __builtin_amdgcn_mfma_f32_16x16x32_bf16(Ax[ks], Wb[nt][ks], vacc[nt], 0, 0, 0);
        }
#pragma unroll
    for (int r = 0; r < 4; ++r) {
        const int node = n0 + q * 4 + r;
        uint2 pu;
        pu.x = (unsigned)f2bf(uacc[0][r] + b1L[0]) | ((unsigned)f2bf(uacc[1][r] + b1L[1]) << 16);
        pu.y = (unsigned)f2bf(uacc[2][r] + b1L[2]) | ((unsigned)f2bf(uacc[3][r] + b1L[3]) << 16);
        *(uint2*)(u_bf + (size_t)node * 64 + c * 4) = pu;
        uint2 pk;
        pk.x = (unsigned)f2bf(vacc[0][r]) | ((unsigned)f2bf(vacc[1][r]) << 16);
        pk.y = (unsigned)f2bf(vacc[2][r]) | ((unsigned)f2bf(vacc[3][r]) << 16);
        *(uint2*)(xv + (size_t)node * 128 + c * 8 + 4) = pk;
    }
}

// ---------------------------------------------------------------------------
// scanA: exclusive scan of bucketCnt (1563 bins, 2 bins/thread) -> baseA+cursA
// ---------------------------------------------------------------------------
__global__ __launch_bounds__(1024) void scanA(
    const int* __restrict__ bucketCnt, int* __restrict__ baseA,
    int* __restrict__ cursA) {
    __shared__ int wsum[16];
    const int t = threadIdx.x, lane = t & 63, w = t >> 6;
    const int i0 = 2 * t, i1 = 2 * t + 1;
    const int v0 = (i0 < N_BUCKETS) ? bucketCnt[i0] : 0;
    const int v1 = (i1 < N_BUCKETS) ? bucketCnt[i1] : 0;
    const int v = v0 + v1;
    int sc = v;
#pragma unroll
    for (int off = 1; off < 64; off <<= 1) {
        int u = __shfl_up(sc, off);
        if (lane >= off) sc += u;
    }
    if (lane == 63) wsum[w] = sc;
    __syncthreads();
    if (w == 0) {
        int x = (lane < 16) ? wsum[lane] : 0;
#pragma unroll
        for (int off = 1; off < 16; off <<= 1) {
            int u = __shfl_up(x, off);
            if (lane >= off) x += u;
        }
        if (lane < 16) wsum[lane] = x;
    }
    __syncthreads();
    const int excl = sc - v + ((w > 0) ? wsum[w - 1] : 0);
    if (i0 < N_BUCKETS) { baseA[i0] = excl; cursA[i0] = excl; }
    if (i1 < N_BUCKETS) { baseA[i1] = excl + v0; cursA[i1] = excl + v0; }
    if (i1 == N_BUCKETS) baseA[N_BUCKETS] = excl + v0;  // NB odd: i1==NB at t=781
}

// ---------------------------------------------------------------------------
// scatterA: stage edges into 64-row bucket regions (block-burst claims).
// rec = {col | lrow<<17, dist(bf16 lo) | emask*0.01 (bf16 hi)}
// ---------------------------------------------------------------------------
__global__ __launch_bounds__(256) void scatterA(
    const int* __restrict__ edges, const float* __restrict__ dist,
    const float* __restrict__ emask, int* __restrict__ cursA,
    uint2* __restrict__ srec) {
    __shared__ int lh[N_BUCKETS];
    __shared__ int lb[N_BUCKETS];
    const int tid = threadIdx.x;
    for (int i = tid; i < N_BUCKETS; i += 256) lh[i] = 0;
    __syncthreads();

    const int e0 = blockIdx.x * 2048 + tid * 8;
    int row[8], col[8];
    unsigned de[8];
#pragma unroll
    for (int i = 0; i < 8; ++i) {
        const int e = e0 + i;
        if (e < N_EDGES) {
            row[i] = edges[e];
            col[i] = edges[N_EDGES + e];
            de[i] = (unsigned)f2bf(dist[e]) | ((unsigned)f2bf(emask[e] * NORM_INV) << 16);
            atomicAdd(&lh[row[i] >> 6], 1);
        } else {
            row[i] = -1;
        }
    }
    __syncthreads();
    for (int b = tid; b < N_BUCKETS; b += 256) {
        const int c = lh[b];
        lb[b] = c ? atomicAdd(&cursA[b], c) : 0;
    }
    __syncthreads();
    for (int i = tid; i < N_BUCKETS; i += 256) lh[i] = 0;
    __syncthreads();
#pragma unroll
    for (int i = 0; i < 8; ++i) {
        if (row[i] >= 0) {
            const int bk = row[i] >> 6;
            const int rk = atomicAdd(&lh[bk], 1);
            uint2 rc;
            rc.x = (unsigned)col[i] | ((unsigned)(row[i] & 63) << 17);
            rc.y = de[i];
            srec[lb[bk] + rk] = rc;
        }
    }
}

// ---------------------------------------------------------------------------
// agg_sort: one block per 64-row bucket. Chunked (1024) in-LDS counting sort
// by local row (int LDS atomics), then row-contiguous processing with
// REGISTER accumulation (4 edge-slots x 16 lanes, DPP reduction, 1-step
// gather prefetch). Wave-owned rows -> plain LDS acc writes (no fp32
// atomics). Fused residual + LN + SiLU. LDS ~25 KB -> 6 blocks/CU.
// ---------------------------------------------------------------------------
__global__ __launch_bounds__(256, 6) void agg_sort(
    const int* __restrict__ baseA, const uint2* __restrict__ srec,
    const unsigned short* __restrict__ xv, const unsigned short* __restrict__ u_bf,
    const float2* __restrict__ tab2, const float* __restrict__ att_b2,
    const float* __restrict__ ln_g, const float* __restrict__ ln_b,
    float* __restrict__ out) {
    __shared__ __align__(16) uint2 sorted[1024];   // 8 KB
    __shared__ __align__(16) float acc[64 * 64];   // 16 KB
    __shared__ int hist[64], roff[64], cur[64];

    const int tid = threadIdx.x;
    const int lane = tid & 63;
    const int wv = tid >> 6;
    const int j = lane & 15;
    const int s = lane >> 4;
    const int b = blockIdx.x;
    const int row0 = b * 64;
    const int nrows = min(64, N_NODES - row0);

    {
        f32x4* a4 = (f32x4*)acc;
        const f32x4 z = {0.f, 0.f, 0.f, 0.f};
        for (int i = tid; i < 1024; i += 256) a4[i] = z;
    }

    const float2 t0 = tab2[j], t1 = tab2[j + 16], t2 = tab2[j + 32], t3 = tab2[j + 48];
    const float b2L = att_b2[0] * L2E;
    const int s0 = baseA[b];
    const int s1 = baseA[b + 1];
    const unsigned* xvu = (const unsigned*)xv;

    for (int c0 = s0; c0 < s1; c0 += 1024) {
        const int m = min(1024, s1 - c0);
        if (tid < 64) hist[tid] = 0;
        __syncthreads();
        for (int i = tid; i < m; i += 256)
            atomicAdd(&hist[srec[c0 + i].x >> 17], 1);
        __syncthreads();
        if (wv == 0) {
            const int v = hist[lane];
            int sc = v;
#pragma unroll
            for (int off = 1; off < 64; off <<= 1) {
                int u = __shfl_up(sc, off);
                if (lane >= off) sc += u;
            }
            roff[lane] = sc - v;
            cur[lane] = sc - v;
        }
        __syncthreads();
        for (int i = tid; i < m; i += 256) {
            const uint2 rc = srec[c0 + i];
            const int rk = atomicAdd(&cur[rc.x >> 17], 1);
            sorted[rk] = rc;
        }
        __syncthreads();

        // process rows owned by this wave (r % 4 == wv)
        for (int r = wv; r < 64; r += 4) {
            const int cnt = hist[r];
            if (cnt == 0) continue;
            const int beg = roff[r];
            const int end = beg + cnt;

            const uint2 uu = *(const uint2*)(u_bf + (size_t)(row0 + r) * 64 + j * 4);
            const float u0 = __uint_as_float(uu.x << 16);
            const float u1 = __uint_as_float(uu.x & 0xffff0000u);
            const float u2 = __uint_as_float(uu.y << 16);
            const float u3 = __uint_as_float(uu.y & 0xffff0000u);

            float a0 = 0.f, a1 = 0.f, a2 = 0.f, a3 = 0.f;
            int idx = min(beg + s, end - 1);
            uint2 rc = sorted[idx];
            uint4 xva = *(const uint4*)(xvu + (size_t)(rc.x & 0x1FFFF) * 64 + j * 4);
            for (int i = beg; i < end; i += 4) {
                const int nidx = min(i + 4 + s, end - 1);
                const uint2 nrc = sorted[nidx];
                const uint4 nxv = *(const uint4*)(xvu + (size_t)(nrc.x & 0x1FFFF) * 64 + j * 4);

                const float dist = __uint_as_float(rc.y << 16);
                const float emN = ((i + s) < end) ? __uint_as_float(rc.y & 0xffff0000u) : 0.f;
                const float x0 = __uint_as_float(xva.x << 16);
                const float x1 = __uint_as_float(xva.x & 0xffff0000u);
                const float x2 = __uint_as_float(xva.y << 16);
                const float x3 = __uint_as_float(xva.y & 0xffff0000u);
                const float v0 = __uint_as_float(xva.z << 16);
                const float v1 = __uint_as_float(xva.z & 0xffff0000u);
                const float v2 = __uint_as_float(xva.w << 16);
                const float v3 = __uint_as_float(xva.w & 0xffff0000u);

                float pv = 0.f, pre, sg;
                pre = fmaf(dist, t0.y, u0) + v0;
                sg = __builtin_amdgcn_rcpf(1.f + __builtin_amdgcn_exp2f(-pre));
                pv = fmaf(pre * sg, t0.x, pv);
                pre = fmaf(dist, t1.y, u1) + v1;
                sg = __builtin_amdgcn_rcpf(1.f + __builtin_amdgcn_exp2f(-pre));
                pv = fmaf(pre * sg, t1.x, pv);
                pre = fmaf(dist, t2.y, u2) + v2;
                sg = __builtin_amdgcn_rcpf(1.f + __builtin_amdgcn_exp2f(-pre));
                pv = fmaf(pre * sg, t2.x, pv);
                pre = fmaf(dist, t3.y, u3) + v3;
                sg = __builtin_amdgcn_rcpf(1.f + __builtin_amdgcn_exp2f(-pre));
                pv = fmaf(pre * sg, t3.x, pv);

                pv = red16(pv);
                const float sp = fmaf(pv, L2E, b2L);
                const float att =
                    emN * __builtin_amdgcn_rcpf(1.f + __builtin_amdgcn_exp2f(-sp));
                a0 = fmaf(att, x0, a0); a1 = fmaf(att, x1, a1);
                a2 = fmaf(att, x2, a2); a3 = fmaf(att, x3, a3);

                rc = nrc; xva = nxv;
            }
            // combine the 4 slots
            a0 += __shfl_xor(a0, 16); a0 += __shfl_xor(a0, 32);
            a1 += __shfl_xor(a1, 16); a1 += __shfl_xor(a1, 32);
            a2 += __shfl_xor(a2, 16); a2 += __shfl_xor(a2, 32);
            a3 += __shfl_xor(a3, 16); a3 += __shfl_xor(a3, 32);
            if (s == 0) {  // plain LDS RMW — this wave owns row r
                f32x4* ap = (f32x4*)(acc + r * 64 + j * 4);
                const f32x4 old = *ap;
                const f32x4 nv = {old.x + a0, old.y + a1, old.z + a2, old.w + a3};
                *ap = nv;
            }
        }
        __syncthreads();  // hist/roff/sorted reused next chunk
    }

    // LN + SiLU epilogue: wave per row, lane = feature
    const int f = lane;
    const int jj = f & 15, kk = f >> 4;
    const float gv = ln_g[f], bv = ln_b[f];
    for (int r = wv; r < nrows; r += 4) {
        const int node = row0 + r;
        const float a = acc[r * 64 + jj * 4 + kk];
        const float xres = bf2f(xv[(size_t)node * 128 + jj * 8 + kk]);
        const float o = xres + a;
        const float sm = red64(o);
        const float sq = red64(o * o);
        const float mu = sm * (1.f / 64.f);
        const float var = sq * (1.f / 64.f) - mu * mu;
        const float rstd = rsqrtf(var + LN_EPS);
        const float y = fmaf((o - mu) * rstd, gv, bv);
        out[(size_t)node * 64 + f] =
            y * __builtin_amdgcn_rcpf(1.f + __builtin_amdgcn_exp2f(-y * L2E));
    }
}

extern "C" void kernel_launch(void* const* d_in, const int* in_sizes, int n_in,
                              void* d_out, int out_size, void* d_ws, size_t ws_size,
                              hipStream_t stream) {
    const float* h      = (const float*)d_in[0];
    const float* dist   = (const float*)d_in[1];
    const int*   edges  = (const int*)d_in[2];
    const float* emask  = (const float*)d_in[4];
    const float* W_lin  = (const float*)d_in[5];
    const float* b_lin  = (const float*)d_in[6];
    const float* att_W1 = (const float*)d_in[7];
    const float* att_b1 = (const float*)d_in[8];
    const float* att_W2 = (const float*)d_in[9];
    const float* att_b2 = (const float*)d_in[10];
    const float* ln_g   = (const float*)d_in[11];
    const float* ln_b   = (const float*)d_in[12];
    float* out = (float*)d_out;

    char* ws = (char*)d_ws;
    unsigned short* xv   = (unsigned short*)ws;                  // 25.6 MB
    unsigned short* u_bf = (unsigned short*)(ws + 25600000);     // 12.8 MB
    uint2* srec          = (uint2*)(ws + 38400000);              // 8 MB
    int* bucketCnt       = (int*)(ws + 46400000);                // 6.3 KB
    int* baseA           = (int*)(ws + 46408192);                // 6.3 KB
    int* cursA           = (int*)(ws + 46416384);                // 6.3 KB
    float2* tab2         = (float2*)(ws + 46424576);             // 512 B
    short8* whi          = (short8*)(ws + 46425088);
    short8* wlo          = (short8*)(ws + 46433280);
    short8* wa           = (short8*)(ws + 46441472);
    short8* wb           = (short8*)(ws + 46449664);

    prep_frags<<<2, 256, 0, stream>>>(W_lin, att_W1, att_W2, whi, wlo, wa, wb,
                                      tab2, bucketCnt);
    proj_hist<<<PROJ_BLOCKS + HISTB, 256, 0, stream>>>(
        h, b_lin, att_b1, whi, wlo, wa, wb, edges, bucketCnt, xv, u_bf);
    scanA<<<1, 1024, 0, stream>>>(bucketCnt, baseA, cursA);
    scatterA<<<HISTB, 256, 0, stream>>>(edges, dist, emask, cursA, srec);
    agg_sort<<<N_BUCKETS, 256, 0, stream>>>(baseA, srec, xv, u_bf, tab2,
                                            att_b2, ln_g, ln_b, out);
}